// Round 1
// baseline (120.348 us; speedup 1.0000x reference)
//
#include <hip/hip_runtime.h>

typedef __bf16 bf16x8 __attribute__((ext_vector_type(8)));
typedef __bf16 bf16x4 __attribute__((ext_vector_type(4)));
typedef float floatx4 __attribute__((ext_vector_type(4)));

#define NENT 237
#define NREL 237
#define D 128
#define B_TRIPLES 16384
#define LDSP 72   // 64 k-elements + 8 pad (144 B pitch -> 2-way bank aliasing, free)

// proj[r][e][j] = sum_d ent_emb[e][d] * rel_W[r][d][j]
// One block computes a 128-row slab of one relation's 237x128 output.
// K=128 staged in two 64-wide halves (LDS 2*18KB fits easily, 4 blocks/CU).
__global__ __launch_bounds__(256) void proj_gemm(
    const float* __restrict__ ent_emb,   // (N, 128) fp32, only rows <237 used
    const float* __restrict__ rel_W,     // (237, 128, 128) fp32
    float* __restrict__ proj)            // (237, 237, 128) fp32 (workspace)
{
  const int r  = blockIdx.y;
  const int m0 = blockIdx.x * 128;       // 0 or 128
  const int tid = threadIdx.x;

  __shared__ __bf16 sE[128 * LDSP];      // A: sE[m][k]   (row-major, k contiguous)
  __shared__ __bf16 sW[128 * LDSP];      // B^T: sW[n][k] = W[k][n]

  const int wave = tid >> 6;
  const int lane = tid & 63;
  const int lrow = lane & 15;
  const int quad = lane >> 4;
  const int r0 = wave * 32;              // wave's 32-row stripe

  floatx4 acc[2][8];
#pragma unroll
  for (int tr = 0; tr < 2; ++tr)
#pragma unroll
    for (int tc = 0; tc < 8; ++tc)
      acc[tr][tc] = (floatx4){0.f, 0.f, 0.f, 0.f};

  for (int kh = 0; kh < 2; ++kh) {
    if (kh) __syncthreads();             // MFMA reads of prev half done

    // --- stage E (fp32 -> bf16), 128 rows x 64 k ---
    {
      const int row  = tid >> 1;           // 0..127
      const int half = (tid & 1) * 32;     // k sub-offset
      const float* src = ent_emb + (size_t)(m0 + row) * D + kh * 64 + half;
      __bf16* dst = sE + row * LDSP + half;
#pragma unroll
      for (int i = 0; i < 8; ++i) {
        float4 v = ((const float4*)src)[i];
        bf16x4 pk = { (__bf16)v.x, (__bf16)v.y, (__bf16)v.z, (__bf16)v.w };
        *(bf16x4*)(dst + i * 4) = pk;
      }
    }
    // --- stage W transposed (fp32 -> bf16): sW[n][k_local] = W[kh*64+k_local][n] ---
    {
      const int kl = tid >> 2;             // 0..63
      const int nq = (tid & 3) * 32;       // n sub-offset
      const float* src = rel_W + ((size_t)r * D + kh * 64 + kl) * D + nq;
#pragma unroll
      for (int i = 0; i < 8; ++i) {
        float4 v = ((const float4*)src)[i];
        const int n = nq + i * 4;
        sW[(n + 0) * LDSP + kl] = (__bf16)v.x;
        sW[(n + 1) * LDSP + kl] = (__bf16)v.y;
        sW[(n + 2) * LDSP + kl] = (__bf16)v.z;
        sW[(n + 3) * LDSP + kl] = (__bf16)v.w;
      }
    }
    __syncthreads();

    // --- MFMA: 2 k-steps of 32 over this half ---
#pragma unroll
    for (int kk = 0; kk < 2; ++kk) {
      const int k0 = kk * 32 + quad * 8;
      bf16x8 a[2], b[8];
#pragma unroll
      for (int tr = 0; tr < 2; ++tr)
        a[tr] = *(const bf16x8*)&sE[(r0 + tr * 16 + lrow) * LDSP + k0];
#pragma unroll
      for (int tc = 0; tc < 8; ++tc)
        b[tc] = *(const bf16x8*)&sW[(tc * 16 + lrow) * LDSP + k0];
#pragma unroll
      for (int tr = 0; tr < 2; ++tr)
#pragma unroll
        for (int tc = 0; tc < 8; ++tc)
          acc[tr][tc] = __builtin_amdgcn_mfma_f32_16x16x32_bf16(
              a[tr], b[tc], acc[tr][tc], 0, 0, 0);
    }
  }

  // --- store: D[m][n], m = quad*4 + reg (verified m89/m91 layout), n = lrow ---
#pragma unroll
  for (int tr = 0; tr < 2; ++tr) {
    const int ebase = m0 + r0 + tr * 16 + quad * 4;
#pragma unroll
    for (int reg = 0; reg < 4; ++reg) {
      const int e = ebase + reg;
      if (e < NENT) {
        float* dst = proj + ((size_t)r * NENT + e) * D;
#pragma unroll
        for (int tc = 0; tc < 8; ++tc)
          dst[tc * 16 + lrow] = acc[tr][tc][reg];
      }
    }
  }
}

// out[b] = fc_b + sum_{c,j} relu(w0[c]*ph[j] + w1[c]*re[j] + w2[c]*pt[j] + cb[c]) * fcw[c*128+j]
// One wave per triple; lane handles dims j=lane and j=lane+64.
__global__ __launch_bounds__(256) void conv_fc(
    const int*   __restrict__ triples,   // (B,3)
    const float* __restrict__ rel_emb,   // (237,128)
    const float* __restrict__ conv_w,    // (50,3)
    const float* __restrict__ conv_b,    // (50)
    const float* __restrict__ fc_w,      // (6400)
    const float* __restrict__ fc_b,      // (1)
    const float* __restrict__ proj,      // (237,237,128)
    float*       __restrict__ out)       // (B,)
{
  const int tid  = threadIdx.x;
  const int wave = tid >> 6;
  const int lane = tid & 63;
  const int b    = blockIdx.x * 4 + wave;

  const int h = triples[b * 3 + 0];
  const int r = triples[b * 3 + 1];
  const int t = triples[b * 3 + 2];

  const float* ph = proj + ((size_t)r * NENT + h) * D;
  const float* pt = proj + ((size_t)r * NENT + t) * D;
  const float* re = rel_emb + (size_t)r * D;

  const float ph0 = ph[lane], ph1 = ph[lane + 64];
  const float pt0 = pt[lane], pt1 = pt[lane + 64];
  const float re0 = re[lane], re1 = re[lane + 64];

  float acc = 0.f;
#pragma unroll 10
  for (int c = 0; c < 50; ++c) {
    const float w0 = conv_w[c * 3 + 0];
    const float w1 = conv_w[c * 3 + 1];
    const float w2 = conv_w[c * 3 + 2];
    const float bc = conv_b[c];
    float f0 = fmaf(w0, ph0, fmaf(w1, re0, fmaf(w2, pt0, bc)));
    float f1 = fmaf(w0, ph1, fmaf(w1, re1, fmaf(w2, pt1, bc)));
    f0 = f0 > 0.f ? f0 : 0.f;
    f1 = f1 > 0.f ? f1 : 0.f;
    acc = fmaf(f0, fc_w[c * D + lane], acc);
    acc = fmaf(f1, fc_w[c * D + lane + 64], acc);
  }
#pragma unroll
  for (int off = 32; off; off >>= 1) acc += __shfl_down(acc, off, 64);
  if (lane == 0) out[b] = acc + fc_b[0];
}

extern "C" void kernel_launch(void* const* d_in, const int* in_sizes, int n_in,
                              void* d_out, int out_size, void* d_ws, size_t ws_size,
                              hipStream_t stream) {
  const int*   triples = (const int*)  d_in[0];
  const float* ent_emb = (const float*)d_in[1];
  const float* rel_emb = (const float*)d_in[2];
  const float* rel_W   = (const float*)d_in[3];
  const float* conv_w  = (const float*)d_in[4];
  const float* conv_b  = (const float*)d_in[5];
  const float* fc_w    = (const float*)d_in[6];
  const float* fc_b    = (const float*)d_in[7];
  float* out  = (float*)d_out;
  float* proj = (float*)d_ws;            // 237*237*128 fp32 = 28.8 MB

  dim3 g1(2, NREL);
  proj_gemm<<<g1, 256, 0, stream>>>(ent_emb, rel_W, proj);
  conv_fc<<<B_TRIPLES / 4, 256, 0, stream>>>(triples, rel_emb, conv_w, conv_b,
                                             fc_w, fc_b, proj, out);
}